// Round 6
// baseline (985.833 us; speedup 1.0000x reference)
//
#include <hip/hip_runtime.h>
#include <hip/hip_bf16.h>

// KNN top-16: X_test[4096,256] vs X_train[65536,256], fp32 in, int32 idx out.
// Phase 1: fp32->bf16 convert; fp32 train row sq-norms (numpy-pairwise emulation).
// Phase 2: bf16 MFMA approx score GEMM (v = ||b||^2 - 2 a.b) + push-based per-row
//          top-16 per 4096-col chunk. 512-thr blocks (2x4 wave grid, 64x32 wave
//          tiles) for 16 waves/CU; global_load_lds(16B) staging with the XOR
//          swizzle inverted on the GLOBAL address side (LDS dest is wave-uniform
//          base + lane*16 -> LDS fills linearly, lane fetches kg = u^(r&7)).
//          Emits packed u32 keys: (fp32(v+1024) bits & 0xFFFFF000) | idxInChunk.
// Phase 3: approx-prefilter 256 -> 32 candidates (>=10-sigma margin), stage the
//          32 train rows into LDS coalesced, 32 exact fp32-reference-emulating
//          chains (np-pairwise norms, sequential-FMA cross, fl32 combine, sqrtf),
//          lex (d32, gidx) top-16 — fp32 snap-ties resolve by index like top_k.

typedef short bf16x8 __attribute__((ext_vector_type(8)));
typedef float f32x4 __attribute__((ext_vector_type(4)));
typedef unsigned short ushort_t;
typedef unsigned long long u64;

#define K_DIM     256
#define N_TRAIN   65536
#define N_TEST    4096
#define TM        128
#define TN        128
#define NCHUNK    16
#define CHUNK_N   (N_TRAIN / NCHUNK)      // 4096
#define ITERS     (CHUNK_N / TN)          // 32
#define LISTN     16
#define QCAP      16
#define INFF      3.0e38f

// ---------------- numpy pairwise sum emulation (fp32, contract OFF) ----------------
static __device__ __forceinline__ float np_pw_sq128(const float* __restrict__ x) {
    #pragma clang fp contract(off)
    float r0, r1, r2, r3, r4, r5, r6, r7;
    {
        const float4 a = *(const float4*)(x + 0);
        const float4 b = *(const float4*)(x + 4);
        r0 = a.x * a.x; r1 = a.y * a.y; r2 = a.z * a.z; r3 = a.w * a.w;
        r4 = b.x * b.x; r5 = b.y * b.y; r6 = b.z * b.z; r7 = b.w * b.w;
    }
    for (int i = 8; i < 128; i += 8) {
        const float4 a = *(const float4*)(x + i);
        const float4 b = *(const float4*)(x + i + 4);
        r0 = r0 + a.x * a.x; r1 = r1 + a.y * a.y;
        r2 = r2 + a.z * a.z; r3 = r3 + a.w * a.w;
        r4 = r4 + b.x * b.x; r5 = r5 + b.y * b.y;
        r6 = r6 + b.z * b.z; r7 = r7 + b.w * b.w;
    }
    return ((r0 + r1) + (r2 + r3)) + ((r4 + r5) + (r6 + r7));
}

// ---------------- async global->LDS, 16B per lane ----------------
static __device__ __forceinline__ void gld_lds16(const ushort_t* g, ushort_t* l) {
    __builtin_amdgcn_global_load_lds(
        (const __attribute__((address_space(1))) unsigned int*)g,
        (__attribute__((address_space(3))) unsigned int*)l,
        16, 0, 0);
}

// ---------------- Phase 1a: convert ----------------
static __device__ __forceinline__ ushort_t f2bf(float x) {
    unsigned u = __float_as_uint(x);
    return (ushort_t)((u + 0x7FFFu + ((u >> 16) & 1u)) >> 16);  // RNE
}

__global__ __launch_bounds__(256) void convert_bf16(
    const float* __restrict__ src, ushort_t* __restrict__ dst, int nrows)
{
    const int wid = threadIdx.x >> 6, lane = threadIdx.x & 63;
    const int row = blockIdx.x * 4 + wid;
    if (row >= nrows) return;
    const float4 f = *(const float4*)(src + (size_t)row * K_DIM + lane * 4);
    ushort4 h;
    h.x = f2bf(f.x); h.y = f2bf(f.y); h.z = f2bf(f.z); h.w = f2bf(f.w);
    *(ushort4*)(dst + (size_t)row * K_DIM + lane * 4) = h;
}

// ---------------- Phase 1b: train row norms, numpy-pairwise fp32 ----------------
__global__ __launch_bounds__(256) void train_sq_np(
    const float* __restrict__ train, float* __restrict__ bsq)
{
    const int r = blockIdx.x * 256 + threadIdx.x;
    const float* x = train + (size_t)r * K_DIM;
    bsq[r] = np_pw_sq128(x) + np_pw_sq128(x + 128);
}

// ---------------- Phase 2: approx GEMM + push-based per-row top-16 ----------------
__global__ __launch_bounds__(512, 4) void knn_approx(
    const ushort_t* __restrict__ testBf, const ushort_t* __restrict__ trainBf,
    const float* __restrict__ bsq, unsigned* __restrict__ cand)
{
    __shared__ __align__(16) ushort_t sA[TM * 64];
    __shared__ __align__(16) ushort_t sB[TN * 64];
    __shared__ float sQv [TM * QCAP];
    __shared__ int   sQc [TM * QCAP];
    __shared__ int   sQn [TM];
    __shared__ float sCut[TM];
    __shared__ float sBsq[TN];

    const int tid = threadIdx.x;
    const int bx = blockIdx.x;
    const int chunk = bx & (NCHUNK - 1);
    const int rowTile = bx >> 4;
    const int rowBase = rowTile * TM;
    const int chunkBase = chunk * CHUNK_N;
    const int lane = tid & 63;
    const int wid = tid >> 6;          // 0..7
    const int quad = lane >> 4;
    const int l15 = lane & 15;
    const int wm = wid >> 2;           // 0..1 (row 64-half)
    const int wn = wid & 3;            // 0..3 (col 32-quarter)

    if (tid < TM) { sQn[tid] = 0; sCut[tid] = INFF; }

    // owner (tid<128) register-resident sorted-ascending top-16 list
    float lv[LISTN]; int lc[LISTN];
    #pragma unroll
    for (int j = 0; j < LISTN; ++j) { lv[j] = INFF; lc[j] = chunkBase + j; }

    for (int it = 0; it < ITERS; ++it) {
        const int colBase = chunkBase + it * TN;
        f32x4 acc[4][2] = {};

        #pragma unroll 1
        for (int p = 0; p < 4; ++p) {
            if (p) __syncthreads();    // p==0 covered by prior iter's sync_or barrier
            // stage A: 1024 16B-slots, linear LDS fill; swizzle inverted on gaddr
            #pragma unroll
            for (int c = 0; c < 2; ++c) {
                const int s = c * 512 + tid;
                const int r = s >> 3, u = s & 7;
                const int kg = u ^ (r & 7);
                gld_lds16(testBf + (size_t)(rowBase + r) * K_DIM + p * 64 + kg * 8,
                          sA + s * 8);
            }
            #pragma unroll
            for (int c = 0; c < 2; ++c) {
                const int s = c * 512 + tid;
                const int r = s >> 3, u = s & 7;
                const int kg = u ^ (r & 7);
                gld_lds16(trainBf + (size_t)(colBase + r) * K_DIM + p * 64 + kg * 8,
                          sB + s * 8);
            }
            if (p == 0 && tid < TN) sBsq[tid] = bsq[colBase + tid];
            __syncthreads();           // drains vmcnt -> LDS valid

            #pragma unroll
            for (int s2 = 0; s2 < 2; ++s2) {
                bf16x8 af[4], bfr[2];
                #pragma unroll
                for (int im = 0; im < 4; ++im) {
                    const int row = wm * 64 + im * 16 + l15;
                    const int pg = ((s2 << 2) | quad) ^ (row & 7);
                    af[im] = *(const bf16x8*)(sA + row * 64 + (pg << 3));
                }
                #pragma unroll
                for (int in = 0; in < 2; ++in) {
                    const int col = wn * 32 + in * 16 + l15;
                    const int pg = ((s2 << 2) | quad) ^ (col & 7);
                    bfr[in] = *(const bf16x8*)(sB + col * 64 + (pg << 3));
                }
                #pragma unroll
                for (int im = 0; im < 4; ++im)
                    #pragma unroll
                    for (int in = 0; in < 2; ++in)
                        acc[im][in] = __builtin_amdgcn_mfma_f32_16x16x32_bf16(
                            af[im], bfr[in], acc[im][in], 0, 0, 0);
            }
        }

        // v = bsq[col] - 2*dot; C layout: row=quad*4+r, col=l15
        float bq[2];
        #pragma unroll
        for (int in = 0; in < 2; ++in) bq[in] = sBsq[wn * 32 + in * 16 + l15];
        #pragma unroll
        for (int im = 0; im < 4; ++im)
            #pragma unroll
            for (int in = 0; in < 2; ++in)
                #pragma unroll
                for (int r = 0; r < 4; ++r)
                    acc[im][in][r] = fmaf(-2.0f, acc[im][in][r], bq[in]);

        // ---- push-based selection; bounded retry rounds on stack overflow ----
        u64 pend = 0xFFFFFFFFULL;                   // 32 values per thread
        while (true) {
            u64 np = 0ULL;
            #pragma unroll
            for (int im = 0; im < 4; ++im)
                #pragma unroll
                for (int in = 0; in < 2; ++in)
                    #pragma unroll
                    for (int r = 0; r < 4; ++r) {
                        const int bitIdx = (im * 2 + in) * 4 + r;
                        if ((pend >> bitIdx) & 1ULL) {
                            const int row = wm * 64 + im * 16 + quad * 4 + r;
                            const float v = acc[im][in][r];
                            if (v < sCut[row]) {
                                const int pos = atomicAdd(&sQn[row], 1);
                                if (pos < QCAP) {
                                    sQv[row * QCAP + pos] = v;
                                    sQc[row * QCAP + pos] = colBase + wn * 32 + in * 16 + l15;
                                } else {
                                    np |= (1ULL << bitIdx);
                                }
                            }
                        }
                    }
            __syncthreads();                        // pushes done before drain
            if (tid < TM) {
                const int n = min(sQn[tid], QCAP);
                for (int e = 0; e < n; ++e) {
                    const float v = sQv[tid * QCAP + e];
                    if (v < lv[LISTN - 1]) {
                        lv[LISTN - 1] = v; lc[LISTN - 1] = sQc[tid * QCAP + e];
                        #pragma unroll
                        for (int j = LISTN - 1; j > 0; --j)
                            if (lv[j] < lv[j - 1]) {
                                const float tv = lv[j]; lv[j] = lv[j - 1]; lv[j - 1] = tv;
                                const int tc = lc[j]; lc[j] = lc[j - 1]; lc[j - 1] = tc;
                            }
                    }
                }
                sQn[tid] = 0;
                sCut[tid] = lv[LISTN - 1];
            }
            if (!__syncthreads_or(np != 0ULL)) break;  // also publishes sCut/sQn
            pend = np;
        }
    }

    if (tid < TM) {
        #pragma unroll
        for (int j = 0; j < LISTN; ++j) {
            // key: (bits(v+1024) & 0xFFFFF000) | idxInChunk ; +1024 keeps it positive
            const unsigned vb = __float_as_uint(lv[j] + 1024.0f) & 0xFFFFF000u;
            cand[(size_t)(rowBase + tid) * (NCHUNK * LISTN) + chunk * LISTN + j] =
                vb | (unsigned)(lc[j] - chunkBase);
        }
    }
}

// ---------------- Phase 3: prefilter 256->32 + exact fp32-emulating re-rank ----------------
__global__ __launch_bounds__(256) void knn_refine(
    const float* __restrict__ test, const float* __restrict__ train,
    const float* __restrict__ bsq, const unsigned* __restrict__ cand,
    int* __restrict__ out)
{
    __shared__ __align__(16) float sArow[K_DIM];
    __shared__ __align__(16) float sCrow[32 * 260];   // 32 rows, pitch 260 (16B-aligned)
    __shared__ u64 sKey[256];
    __shared__ int sSel[32];
    __shared__ u64 sKey2[32];

    const int row = blockIdx.x, tid = threadIdx.x;
    sArow[tid] = test[(size_t)row * K_DIM + tid];
    {
        const unsigned k = cand[(size_t)row * 256 + tid];
        const int gidx = (tid >> 4) * CHUNK_N + (int)(k & 0xFFFu);
        // lex (value20, gidx17) — unique keys (gidx unique)
        sKey[tid] = ((u64)(k & 0xFFFFF000u) << 5) | (unsigned)gidx;
    }
    __syncthreads();

    if (tid < 64) {   // approx-top-32 of 256 (margin >= ~10 sigma vs rank-33 gap)
        u64 ek[4];
        #pragma unroll
        for (int j = 0; j < 4; ++j) ek[j] = sKey[tid * 4 + j];
        for (int sel = 0; sel < 32; ++sel) {
            u64 bk = ek[0];
            #pragma unroll
            for (int j = 1; j < 4; ++j) bk = (ek[j] < bk) ? ek[j] : bk;
            #pragma unroll
            for (int off = 32; off > 0; off >>= 1) {
                const u64 ok = __shfl_down(bk, off);
                bk = (ok < bk) ? ok : bk;
            }
            bk = __shfl(bk, 0);
            if (tid == 0) sSel[sel] = (int)(bk & 0x1FFFFULL);
            #pragma unroll
            for (int j = 0; j < 4; ++j)
                if (ek[j] == bk) ek[j] = ~0ULL;
        }
    }
    __syncthreads();

    // stage the 32 selected train rows into LDS, coalesced (8 threads/row)
    {
        const int cr = tid >> 3, q = tid & 7;
        const float* src = train + (size_t)sSel[cr] * K_DIM;
        #pragma unroll
        for (int j = 0; j < 8; ++j) {
            const int f4 = q + j * 8;
            *(float4*)(sCrow + cr * 260 + f4 * 4) = *(const float4*)(src + f4 * 4);
        }
    }
    __syncthreads();

    if (tid < 32) {   // exact reference-emulating chains (order-sensitive fp32)
        const int gidx = sSel[tid];
        const float ta = np_pw_sq128(sArow) + np_pw_sq128(sArow + 128);
        const float tb = bsq[gidx];
        const float* bp = sCrow + tid * 260;
        float c = 0.0f;
        #pragma unroll 4
        for (int k = 0; k < K_DIM / 4; ++k) {
            const float4 a = *(const float4*)(sArow + k * 4);
            const float4 b = *(const float4*)(bp + k * 4);
            c = fmaf(a.x, b.x, c); c = fmaf(a.y, b.y, c);
            c = fmaf(a.z, b.z, c); c = fmaf(a.w, b.w, c);
        }
        float d32;
        {
            #pragma clang fp contract(off)
            const float t = ta + tb;
            float s = t - 2.0f * c;
            s = fmaxf(s, 0.0f);
            d32 = sqrtf(s);
        }
        sKey2[tid] = ((u64)__float_as_uint(d32) << 32) | (unsigned)gidx;
    }
    __syncthreads();

    if (tid < 64) {   // final lex (d32, gidx) top-16
        u64 ek = (tid < 32) ? sKey2[tid] : ~0ULL;
        for (int sel = 0; sel < 16; ++sel) {
            u64 bk = ek;
            #pragma unroll
            for (int off = 32; off > 0; off >>= 1) {
                const u64 ok = __shfl_down(bk, off);
                bk = (ok < bk) ? ok : bk;
            }
            bk = __shfl(bk, 0);
            if (tid == 0) out[(size_t)row * 16 + sel] = (int)(bk & 0xFFFFFFFFULL);
            if (ek == bk) ek = ~0ULL;
        }
    }
}

// ---------------- launch ----------------
extern "C" void kernel_launch(void* const* d_in, const int* in_sizes, int n_in,
                              void* d_out, int out_size, void* d_ws, size_t ws_size,
                              hipStream_t stream)
{
    const float* Xtrain = (const float*)d_in[0];   // [65536, 256]
    const float* Xtest  = (const float*)d_in[1];   // [4096, 256]
    int* out = (int*)d_out;                        // [4096, 16] int32

    const size_t OFF_TRAINBF = 0;                              // 33,554,432 B
    const size_t OFF_TESTBF  = 33554432;                       //  2,097,152 B
    const size_t OFF_BSQ     = 35651584;                       //    262,144 B
    const size_t OFF_CAND    = 35913728;                       //  4,194,304 B
    const size_t NEED        = 40108032;
    if (ws_size < NEED) return;

    char* ws = (char*)d_ws;
    ushort_t* trainBf = (ushort_t*)(ws + OFF_TRAINBF);
    ushort_t* testBf  = (ushort_t*)(ws + OFF_TESTBF);
    float*    bsq     = (float*)(ws + OFF_BSQ);
    unsigned* cand    = (unsigned*)(ws + OFF_CAND);

    convert_bf16<<<dim3(N_TRAIN / 4), dim3(256), 0, stream>>>(Xtrain, trainBf, N_TRAIN);
    convert_bf16<<<dim3(N_TEST / 4), dim3(256), 0, stream>>>(Xtest, testBf, N_TEST);
    train_sq_np<<<dim3(N_TRAIN / 256), dim3(256), 0, stream>>>(Xtrain, bsq);
    knn_approx<<<dim3((N_TEST / TM) * NCHUNK), dim3(512), 0, stream>>>(testBf, trainBf, bsq, cand);
    knn_refine<<<dim3(N_TEST), dim3(256), 0, stream>>>(Xtest, Xtrain, bsq, cand, out);
}

// Round 7
// 742.344 us; speedup vs baseline: 1.3280x; 1.3280x over previous
//
#include <hip/hip_runtime.h>
#include <hip/hip_bf16.h>

// KNN top-16: X_test[4096,256] vs X_train[65536,256], fp32 in, int32 idx out.
// Phase 1: fp32->bf16 convert; fp32 train row sq-norms (numpy-pairwise emulation).
// Phase 2: bf16 MFMA approx score GEMM (v = ||b||^2 - 2 a.b) + push-based per-row
//          top-16 per 4096-col chunk. TM=64 tiles -> 1024 blocks of 256 thr,
//          33 KB LDS -> 4 INDEPENDENT blocks/CU (r6 lesson: extra waves inside
//          one barrier domain don't hide the drain; independent blocks do).
//          global_load_lds(16B) staging, XOR swizzle inverted on global side.
// Phase 3: exact fp32-reference-emulating re-rank of 256 candidates/row
//          (np-pairwise norms, sequential-FMA cross, fl32 combine, sqrtf),
//          lex (d32, idx) top-16 — fp32 snap-ties resolve by index like top_k.

typedef short bf16x8 __attribute__((ext_vector_type(8)));
typedef float f32x4 __attribute__((ext_vector_type(4)));
typedef unsigned short ushort_t;
typedef unsigned long long u64;

#define K_DIM     256
#define N_TRAIN   65536
#define N_TEST    4096
#define TM        64
#define TN        128
#define NCHUNK    16
#define CHUNK_N   (N_TRAIN / NCHUNK)      // 4096
#define ITERS     (CHUNK_N / TN)          // 32
#define LISTN     16
#define QCAP      16
#define INFF      3.0e38f

// ---------------- numpy pairwise sum emulation (fp32, contract OFF) ----------------
static __device__ __forceinline__ float np_pw_sq128(const float* __restrict__ x) {
    #pragma clang fp contract(off)
    float r0, r1, r2, r3, r4, r5, r6, r7;
    {
        const float4 a = *(const float4*)(x + 0);
        const float4 b = *(const float4*)(x + 4);
        r0 = a.x * a.x; r1 = a.y * a.y; r2 = a.z * a.z; r3 = a.w * a.w;
        r4 = b.x * b.x; r5 = b.y * b.y; r6 = b.z * b.z; r7 = b.w * b.w;
    }
    for (int i = 8; i < 128; i += 8) {
        const float4 a = *(const float4*)(x + i);
        const float4 b = *(const float4*)(x + i + 4);
        r0 = r0 + a.x * a.x; r1 = r1 + a.y * a.y;
        r2 = r2 + a.z * a.z; r3 = r3 + a.w * a.w;
        r4 = r4 + b.x * b.x; r5 = r5 + b.y * b.y;
        r6 = r6 + b.z * b.z; r7 = r7 + b.w * b.w;
    }
    return ((r0 + r1) + (r2 + r3)) + ((r4 + r5) + (r6 + r7));
}

// ---------------- async global->LDS, 16B per lane ----------------
static __device__ __forceinline__ void gld_lds16(const ushort_t* g, ushort_t* l) {
    __builtin_amdgcn_global_load_lds(
        (const __attribute__((address_space(1))) unsigned int*)g,
        (__attribute__((address_space(3))) unsigned int*)l,
        16, 0, 0);
}

// ---------------- Phase 1a: convert ----------------
static __device__ __forceinline__ ushort_t f2bf(float x) {
    unsigned u = __float_as_uint(x);
    return (ushort_t)((u + 0x7FFFu + ((u >> 16) & 1u)) >> 16);  // RNE
}

__global__ __launch_bounds__(256) void convert_bf16(
    const float* __restrict__ src, ushort_t* __restrict__ dst, int nrows)
{
    const int wid = threadIdx.x >> 6, lane = threadIdx.x & 63;
    const int row = blockIdx.x * 4 + wid;
    if (row >= nrows) return;
    const float4 f = *(const float4*)(src + (size_t)row * K_DIM + lane * 4);
    ushort4 h;
    h.x = f2bf(f.x); h.y = f2bf(f.y); h.z = f2bf(f.z); h.w = f2bf(f.w);
    *(ushort4*)(dst + (size_t)row * K_DIM + lane * 4) = h;
}

// ---------------- Phase 1b: train row norms, numpy-pairwise fp32 ----------------
__global__ __launch_bounds__(256) void train_sq_np(
    const float* __restrict__ train, float* __restrict__ bsq)
{
    const int r = blockIdx.x * 256 + threadIdx.x;
    const float* x = train + (size_t)r * K_DIM;
    bsq[r] = np_pw_sq128(x) + np_pw_sq128(x + 128);
}

// ---------------- Phase 2: approx GEMM + push-based per-row top-16 ----------------
// 256 thr, 2x2 wave grid, wave-tile 32x64, acc[2][4] (32 values/thread).
// LDS ~33 KB -> 4 independent blocks/CU.
__global__ __launch_bounds__(256, 4) void knn_approx(
    const ushort_t* __restrict__ testBf, const ushort_t* __restrict__ trainBf,
    const float* __restrict__ bsq, int* __restrict__ cand)
{
    __shared__ __align__(16) ushort_t sA[TM * 64];     //  8 KB
    __shared__ __align__(16) ushort_t sB[TN * 64];     // 16 KB
    __shared__ float sQv [TM * QCAP];                  //  4 KB
    __shared__ int   sQc [TM * QCAP];                  //  4 KB
    __shared__ int   sQn [TM];
    __shared__ float sCut[TM];
    __shared__ float sBsq[TN];

    const int tid = threadIdx.x;
    const int bx = blockIdx.x;
    const int chunk = bx & (NCHUNK - 1);
    const int rowTile = bx >> 4;                       // 0..63
    const int rowBase = rowTile * TM;
    const int chunkBase = chunk * CHUNK_N;
    const int lane = tid & 63;
    const int wid = tid >> 6;
    const int quad = lane >> 4;
    const int l15 = lane & 15;
    const int wm = wid >> 1;           // 0..1 (row 32-half)
    const int wn = wid & 1;            // 0..1 (col 64-half)

    if (tid < TM) { sQn[tid] = 0; sCut[tid] = INFF; }

    // owner (tid<64) register-resident sorted-ascending top-16 list
    float lv[LISTN]; int lc[LISTN];
    #pragma unroll
    for (int j = 0; j < LISTN; ++j) { lv[j] = INFF; lc[j] = chunkBase + j; }

    for (int it = 0; it < ITERS; ++it) {
        const int colBase = chunkBase + it * TN;
        f32x4 acc[2][4] = {};

        #pragma unroll 1
        for (int p = 0; p < 4; ++p) {
            if (p) __syncthreads();    // p==0 covered by prior sync_or barrier
            // A: 64 rows x 64 k = 512 16B-slots; linear LDS fill, swizzle on gaddr
            {
                const int s = tid, r = s >> 3, u = s & 7;
                const int kg = u ^ (r & 7);
                gld_lds16(testBf + (size_t)(rowBase + r) * K_DIM + p * 64 + kg * 8,
                          sA + s * 8);
            }
            {
                const int s = 256 + tid, r = s >> 3, u = s & 7;
                const int kg = u ^ (r & 7);
                gld_lds16(testBf + (size_t)(rowBase + r) * K_DIM + p * 64 + kg * 8,
                          sA + s * 8);
            }
            // B: 128 rows x 64 k = 1024 16B-slots
            #pragma unroll
            for (int c = 0; c < 4; ++c) {
                const int s = c * 256 + tid, r = s >> 3, u = s & 7;
                const int kg = u ^ (r & 7);
                gld_lds16(trainBf + (size_t)(colBase + r) * K_DIM + p * 64 + kg * 8,
                          sB + s * 8);
            }
            if (p == 0 && tid < TN) sBsq[tid] = bsq[colBase + tid];
            __syncthreads();           // drains vmcnt -> LDS valid

            #pragma unroll
            for (int s2 = 0; s2 < 2; ++s2) {
                bf16x8 af[2], bfr[4];
                #pragma unroll
                for (int im = 0; im < 2; ++im) {
                    const int row = wm * 32 + im * 16 + l15;
                    const int pg = ((s2 << 2) | quad) ^ (row & 7);
                    af[im] = *(const bf16x8*)(sA + row * 64 + (pg << 3));
                }
                #pragma unroll
                for (int in = 0; in < 4; ++in) {
                    const int col = wn * 64 + in * 16 + l15;
                    const int pg = ((s2 << 2) | quad) ^ (col & 7);
                    bfr[in] = *(const bf16x8*)(sB + col * 64 + (pg << 3));
                }
                #pragma unroll
                for (int im = 0; im < 2; ++im)
                    #pragma unroll
                    for (int in = 0; in < 4; ++in)
                        acc[im][in] = __builtin_amdgcn_mfma_f32_16x16x32_bf16(
                            af[im], bfr[in], acc[im][in], 0, 0, 0);
            }
        }

        // v = bsq[col] - 2*dot; C layout: row=quad*4+r, col=l15
        float bq[4];
        #pragma unroll
        for (int in = 0; in < 4; ++in) bq[in] = sBsq[wn * 64 + in * 16 + l15];
        #pragma unroll
        for (int im = 0; im < 2; ++im)
            #pragma unroll
            for (int in = 0; in < 4; ++in)
                #pragma unroll
                for (int r = 0; r < 4; ++r)
                    acc[im][in][r] = fmaf(-2.0f, acc[im][in][r], bq[in]);

        // ---- push-based selection; bounded retry rounds on stack overflow ----
        u64 pend = 0xFFFFFFFFULL;                   // 32 values per thread
        while (true) {
            // hoist this thread's 8 row-cutoffs into regs (8 ds_reads per round)
            float cutr[2][4];
            #pragma unroll
            for (int im = 0; im < 2; ++im)
                #pragma unroll
                for (int r = 0; r < 4; ++r)
                    cutr[im][r] = sCut[wm * 32 + im * 16 + quad * 4 + r];

            u64 np = 0ULL;
            #pragma unroll
            for (int im = 0; im < 2; ++im)
                #pragma unroll
                for (int in = 0; in < 4; ++in)
                    #pragma unroll
                    for (int r = 0; r < 4; ++r) {
                        const int bitIdx = (im * 4 + in) * 4 + r;
                        if ((pend >> bitIdx) & 1ULL) {
                            const float v = acc[im][in][r];
                            if (v < cutr[im][r]) {
                                const int row = wm * 32 + im * 16 + quad * 4 + r;
                                const int pos = atomicAdd(&sQn[row], 1);
                                if (pos < QCAP) {
                                    sQv[row * QCAP + pos] = v;
                                    sQc[row * QCAP + pos] = colBase + wn * 64 + in * 16 + l15;
                                } else {
                                    np |= (1ULL << bitIdx);
                                }
                            }
                        }
                    }
            __syncthreads();                        // pushes done before drain
            if (tid < TM) {
                const int n = min(sQn[tid], QCAP);
                for (int e = 0; e < n; ++e) {
                    const float v = sQv[tid * QCAP + e];
                    if (v < lv[LISTN - 1]) {
                        lv[LISTN - 1] = v; lc[LISTN - 1] = sQc[tid * QCAP + e];
                        #pragma unroll
                        for (int j = LISTN - 1; j > 0; --j)
                            if (lv[j] < lv[j - 1]) {
                                const float tv = lv[j]; lv[j] = lv[j - 1]; lv[j - 1] = tv;
                                const int tc = lc[j]; lc[j] = lc[j - 1]; lc[j - 1] = tc;
                            }
                    }
                }
                sQn[tid] = 0;
                sCut[tid] = lv[LISTN - 1];
            }
            if (!__syncthreads_or(np != 0ULL)) break;  // also publishes sCut/sQn
            pend = np;
        }
    }

    if (tid < TM) {
        #pragma unroll
        for (int j = 0; j < LISTN; ++j)
            cand[(size_t)(rowBase + tid) * (NCHUNK * LISTN) + chunk * LISTN + j] = lc[j];
    }
}

// ---------------- Phase 3: fp32-reference-emulating re-rank + lex top-16 ----------------
__global__ __launch_bounds__(256) void knn_refine(
    const float* __restrict__ test, const float* __restrict__ train,
    const float* __restrict__ bsq, const int* __restrict__ cand,
    int* __restrict__ out)
{
    __shared__ __align__(16) float sArow[K_DIM];
    __shared__ u64 sKey[256];
    const int row = blockIdx.x, tid = threadIdx.x;
    sArow[tid] = test[(size_t)row * K_DIM + tid];
    const int ci = cand[(size_t)row * 256 + tid];
    __syncthreads();

    const float ta = np_pw_sq128(sArow) + np_pw_sq128(sArow + 128);
    const float tb = bsq[ci];

    const float4* bp = (const float4*)(train + (size_t)ci * K_DIM);
    const float4* ap = (const float4*)sArow;
    float c = 0.0f;
    #pragma unroll 4
    for (int k = 0; k < K_DIM / 4; ++k) {
        const float4 a = ap[k];
        const float4 b = bp[k];
        c = fmaf(a.x, b.x, c); c = fmaf(a.y, b.y, c);
        c = fmaf(a.z, b.z, c); c = fmaf(a.w, b.w, c);
    }

    float d32;
    {
        #pragma clang fp contract(off)
        const float t = ta + tb;
        float s = t - 2.0f * c;
        s = fmaxf(s, 0.0f);
        d32 = sqrtf(s);
    }
    sKey[tid] = ((u64)__float_as_uint(d32) << 32) | (unsigned)ci;
    __syncthreads();

    if (tid < 64) {
        u64 ek[4];
        #pragma unroll
        for (int j = 0; j < 4; ++j) ek[j] = sKey[tid * 4 + j];
        for (int sel = 0; sel < 16; ++sel) {
            u64 bk = ek[0];
            #pragma unroll
            for (int j = 1; j < 4; ++j) bk = (ek[j] < bk) ? ek[j] : bk;
            #pragma unroll
            for (int off = 32; off > 0; off >>= 1) {
                const u64 ok = __shfl_down(bk, off);
                bk = (ok < bk) ? ok : bk;
            }
            bk = __shfl(bk, 0);
            if (tid == 0) out[(size_t)row * 16 + sel] = (int)(bk & 0xFFFFFFFFULL);
            #pragma unroll
            for (int j = 0; j < 4; ++j)
                if (ek[j] == bk) ek[j] = ~0ULL;
        }
    }
}

// ---------------- launch ----------------
extern "C" void kernel_launch(void* const* d_in, const int* in_sizes, int n_in,
                              void* d_out, int out_size, void* d_ws, size_t ws_size,
                              hipStream_t stream)
{
    const float* Xtrain = (const float*)d_in[0];   // [65536, 256]
    const float* Xtest  = (const float*)d_in[1];   // [4096, 256]
    int* out = (int*)d_out;                        // [4096, 16] int32

    const size_t OFF_TRAINBF = 0;                              // 33,554,432 B
    const size_t OFF_TESTBF  = 33554432;                       //  2,097,152 B
    const size_t OFF_BSQ     = 35651584;                       //    262,144 B
    const size_t OFF_CAND    = 35913728;                       //  4,194,304 B
    const size_t NEED        = 40108032;
    if (ws_size < NEED) return;

    char* ws = (char*)d_ws;
    ushort_t* trainBf = (ushort_t*)(ws + OFF_TRAINBF);
    ushort_t* testBf  = (ushort_t*)(ws + OFF_TESTBF);
    float*    bsq     = (float*)(ws + OFF_BSQ);
    int*      cand    = (int*)(ws + OFF_CAND);

    convert_bf16<<<dim3(N_TRAIN / 4), dim3(256), 0, stream>>>(Xtrain, trainBf, N_TRAIN);
    convert_bf16<<<dim3(N_TEST / 4), dim3(256), 0, stream>>>(Xtest, testBf, N_TEST);
    train_sq_np<<<dim3(N_TRAIN / 256), dim3(256), 0, stream>>>(Xtrain, bsq);
    knn_approx<<<dim3((N_TEST / TM) * NCHUNK), dim3(256), 0, stream>>>(testBf, trainBf, bsq, cand);
    knn_refine<<<dim3(N_TEST), dim3(256), 0, stream>>>(Xtest, Xtrain, bsq, cand, out);
}

// Round 8
// 690.352 us; speedup vs baseline: 1.4280x; 1.0753x over previous
//
#include <hip/hip_runtime.h>
#include <hip/hip_bf16.h>

// KNN top-16: X_test[4096,256] vs X_train[65536,256], fp32 in, int32 idx out.
// Phase 1: fp32->bf16 convert; fp32 train row sq-norms (numpy-pairwise emulation).
// Phase 2: bf16 MFMA approx score GEMM (v = ||b||^2 - 2 a.b) + push-based per-row
//          top-16 per 4096-col chunk (r7 structure: TM=64, 4 blocks/CU,
//          global_load_lds(16B), XOR swizzle inverted on the global side).
//          Emits packed u32 keys: (bits(v+1024) & 0xFFFFF000) | idxInChunk.
// Phase 3: 8 rows/block: per-row approx-top-32 prefilter of the 256 candidates
//          (32 extraction rounds over width-32 shuffles; >=10 d^2-unit margin,
//          field-validated in r6), then 256 parallel exact fp32-reference-
//          emulating chains (np-pairwise norms, sequential-FMA cross, fl32
//          combine, sqrtf), lex (d32, gidx) top-16. Cuts refine gather 1.05 GB
//          -> 132 MB (r7's hidden 250 us was MLP-bound L3 gather).

typedef short bf16x8 __attribute__((ext_vector_type(8)));
typedef float f32x4 __attribute__((ext_vector_type(4)));
typedef unsigned short ushort_t;
typedef unsigned long long u64;

#define K_DIM     256
#define N_TRAIN   65536
#define N_TEST    4096
#define TM        64
#define TN        128
#define NCHUNK    16
#define CHUNK_N   (N_TRAIN / NCHUNK)      // 4096
#define ITERS     (CHUNK_N / TN)          // 32
#define LISTN     16
#define QCAP      16
#define RPB       8                        // refine rows per block
#define INFF      3.0e38f

// ---------------- numpy pairwise sum emulation (fp32, contract OFF) ----------------
static __device__ __forceinline__ float np_pw_sq128(const float* __restrict__ x) {
    #pragma clang fp contract(off)
    float r0, r1, r2, r3, r4, r5, r6, r7;
    {
        const float4 a = *(const float4*)(x + 0);
        const float4 b = *(const float4*)(x + 4);
        r0 = a.x * a.x; r1 = a.y * a.y; r2 = a.z * a.z; r3 = a.w * a.w;
        r4 = b.x * b.x; r5 = b.y * b.y; r6 = b.z * b.z; r7 = b.w * b.w;
    }
    for (int i = 8; i < 128; i += 8) {
        const float4 a = *(const float4*)(x + i);
        const float4 b = *(const float4*)(x + i + 4);
        r0 = r0 + a.x * a.x; r1 = r1 + a.y * a.y;
        r2 = r2 + a.z * a.z; r3 = r3 + a.w * a.w;
        r4 = r4 + b.x * b.x; r5 = r5 + b.y * b.y;
        r6 = r6 + b.z * b.z; r7 = r7 + b.w * b.w;
    }
    return ((r0 + r1) + (r2 + r3)) + ((r4 + r5) + (r6 + r7));
}

// ---------------- async global->LDS, 16B per lane ----------------
static __device__ __forceinline__ void gld_lds16(const ushort_t* g, ushort_t* l) {
    __builtin_amdgcn_global_load_lds(
        (const __attribute__((address_space(1))) unsigned int*)g,
        (__attribute__((address_space(3))) unsigned int*)l,
        16, 0, 0);
}

// ---------------- Phase 1a: convert ----------------
static __device__ __forceinline__ ushort_t f2bf(float x) {
    unsigned u = __float_as_uint(x);
    return (ushort_t)((u + 0x7FFFu + ((u >> 16) & 1u)) >> 16);  // RNE
}

__global__ __launch_bounds__(256) void convert_bf16(
    const float* __restrict__ src, ushort_t* __restrict__ dst, int nrows)
{
    const int wid = threadIdx.x >> 6, lane = threadIdx.x & 63;
    const int row = blockIdx.x * 4 + wid;
    if (row >= nrows) return;
    const float4 f = *(const float4*)(src + (size_t)row * K_DIM + lane * 4);
    ushort4 h;
    h.x = f2bf(f.x); h.y = f2bf(f.y); h.z = f2bf(f.z); h.w = f2bf(f.w);
    *(ushort4*)(dst + (size_t)row * K_DIM + lane * 4) = h;
}

// ---------------- Phase 1b: train row norms, numpy-pairwise fp32 ----------------
__global__ __launch_bounds__(256) void train_sq_np(
    const float* __restrict__ train, float* __restrict__ bsq)
{
    const int r = blockIdx.x * 256 + threadIdx.x;
    const float* x = train + (size_t)r * K_DIM;
    bsq[r] = np_pw_sq128(x) + np_pw_sq128(x + 128);
}

// ---------------- Phase 2: approx GEMM + push-based per-row top-16 ----------------
// 256 thr, 2x2 wave grid, wave-tile 32x64, acc[2][4] (32 values/thread).
// LDS ~33 KB -> 4 independent blocks/CU.
__global__ __launch_bounds__(256, 4) void knn_approx(
    const ushort_t* __restrict__ testBf, const ushort_t* __restrict__ trainBf,
    const float* __restrict__ bsq, unsigned* __restrict__ cand)
{
    __shared__ __align__(16) ushort_t sA[TM * 64];     //  8 KB
    __shared__ __align__(16) ushort_t sB[TN * 64];     // 16 KB
    __shared__ float sQv [TM * QCAP];                  //  4 KB
    __shared__ int   sQc [TM * QCAP];                  //  4 KB
    __shared__ int   sQn [TM];
    __shared__ float sCut[TM];
    __shared__ float sBsq[TN];

    const int tid = threadIdx.x;
    const int bx = blockIdx.x;
    const int chunk = bx & (NCHUNK - 1);
    const int rowTile = bx >> 4;                       // 0..63
    const int rowBase = rowTile * TM;
    const int chunkBase = chunk * CHUNK_N;
    const int lane = tid & 63;
    const int wid = tid >> 6;
    const int quad = lane >> 4;
    const int l15 = lane & 15;
    const int wm = wid >> 1;           // 0..1 (row 32-half)
    const int wn = wid & 1;            // 0..1 (col 64-half)

    if (tid < TM) { sQn[tid] = 0; sCut[tid] = INFF; }

    // owner (tid<64) register-resident sorted-ascending top-16 list
    float lv[LISTN]; int lc[LISTN];
    #pragma unroll
    for (int j = 0; j < LISTN; ++j) { lv[j] = INFF; lc[j] = chunkBase + j; }

    for (int it = 0; it < ITERS; ++it) {
        const int colBase = chunkBase + it * TN;
        f32x4 acc[2][4] = {};

        #pragma unroll 1
        for (int p = 0; p < 4; ++p) {
            if (p) __syncthreads();    // p==0 covered by prior sync_or barrier
            // A: 64 rows x 64 k = 512 16B-slots; linear LDS fill, swizzle on gaddr
            {
                const int s = tid, r = s >> 3, u = s & 7;
                const int kg = u ^ (r & 7);
                gld_lds16(testBf + (size_t)(rowBase + r) * K_DIM + p * 64 + kg * 8,
                          sA + s * 8);
            }
            {
                const int s = 256 + tid, r = s >> 3, u = s & 7;
                const int kg = u ^ (r & 7);
                gld_lds16(testBf + (size_t)(rowBase + r) * K_DIM + p * 64 + kg * 8,
                          sA + s * 8);
            }
            // B: 128 rows x 64 k = 1024 16B-slots
            #pragma unroll
            for (int c = 0; c < 4; ++c) {
                const int s = c * 256 + tid, r = s >> 3, u = s & 7;
                const int kg = u ^ (r & 7);
                gld_lds16(trainBf + (size_t)(colBase + r) * K_DIM + p * 64 + kg * 8,
                          sB + s * 8);
            }
            if (p == 0 && tid < TN) sBsq[tid] = bsq[colBase + tid];
            __syncthreads();           // drains vmcnt -> LDS valid

            #pragma unroll
            for (int s2 = 0; s2 < 2; ++s2) {
                bf16x8 af[2], bfr[4];
                #pragma unroll
                for (int im = 0; im < 2; ++im) {
                    const int row = wm * 32 + im * 16 + l15;
                    const int pg = ((s2 << 2) | quad) ^ (row & 7);
                    af[im] = *(const bf16x8*)(sA + row * 64 + (pg << 3));
                }
                #pragma unroll
                for (int in = 0; in < 4; ++in) {
                    const int col = wn * 64 + in * 16 + l15;
                    const int pg = ((s2 << 2) | quad) ^ (col & 7);
                    bfr[in] = *(const bf16x8*)(sB + col * 64 + (pg << 3));
                }
                #pragma unroll
                for (int im = 0; im < 2; ++im)
                    #pragma unroll
                    for (int in = 0; in < 4; ++in)
                        acc[im][in] = __builtin_amdgcn_mfma_f32_16x16x32_bf16(
                            af[im], bfr[in], acc[im][in], 0, 0, 0);
            }
        }

        // v = bsq[col] - 2*dot; C layout: row=quad*4+r, col=l15
        float bq[4];
        #pragma unroll
        for (int in = 0; in < 4; ++in) bq[in] = sBsq[wn * 64 + in * 16 + l15];
        #pragma unroll
        for (int im = 0; im < 2; ++im)
            #pragma unroll
            for (int in = 0; in < 4; ++in)
                #pragma unroll
                for (int r = 0; r < 4; ++r)
                    acc[im][in][r] = fmaf(-2.0f, acc[im][in][r], bq[in]);

        // ---- push-based selection; bounded retry rounds on stack overflow ----
        u64 pend = 0xFFFFFFFFULL;                   // 32 values per thread
        while (true) {
            float cutr[2][4];
            #pragma unroll
            for (int im = 0; im < 2; ++im)
                #pragma unroll
                for (int r = 0; r < 4; ++r)
                    cutr[im][r] = sCut[wm * 32 + im * 16 + quad * 4 + r];

            u64 np = 0ULL;
            #pragma unroll
            for (int im = 0; im < 2; ++im)
                #pragma unroll
                for (int in = 0; in < 4; ++in)
                    #pragma unroll
                    for (int r = 0; r < 4; ++r) {
                        const int bitIdx = (im * 4 + in) * 4 + r;
                        if ((pend >> bitIdx) & 1ULL) {
                            const float v = acc[im][in][r];
                            if (v < cutr[im][r]) {
                                const int row = wm * 32 + im * 16 + quad * 4 + r;
                                const int pos = atomicAdd(&sQn[row], 1);
                                if (pos < QCAP) {
                                    sQv[row * QCAP + pos] = v;
                                    sQc[row * QCAP + pos] = colBase + wn * 64 + in * 16 + l15;
                                } else {
                                    np |= (1ULL << bitIdx);
                                }
                            }
                        }
                    }
            __syncthreads();                        // pushes done before drain
            if (tid < TM) {
                const int n = min(sQn[tid], QCAP);
                for (int e = 0; e < n; ++e) {
                    const float v = sQv[tid * QCAP + e];
                    if (v < lv[LISTN - 1]) {
                        lv[LISTN - 1] = v; lc[LISTN - 1] = sQc[tid * QCAP + e];
                        #pragma unroll
                        for (int j = LISTN - 1; j > 0; --j)
                            if (lv[j] < lv[j - 1]) {
                                const float tv = lv[j]; lv[j] = lv[j - 1]; lv[j - 1] = tv;
                                const int tc = lc[j]; lc[j] = lc[j - 1]; lc[j - 1] = tc;
                            }
                    }
                }
                sQn[tid] = 0;
                sCut[tid] = lv[LISTN - 1];
            }
            if (!__syncthreads_or(np != 0ULL)) break;  // also publishes sCut/sQn
            pend = np;
        }
    }

    if (tid < TM) {
        #pragma unroll
        for (int j = 0; j < LISTN; ++j) {
            // packed key: bits(v+1024)&0xFFFFF000 | idxInChunk (12b); monotone in v
            const unsigned vb = __float_as_uint(lv[j] + 1024.0f) & 0xFFFFF000u;
            cand[(size_t)(rowBase + tid) * (NCHUNK * LISTN) + chunk * LISTN + j] =
                vb | (unsigned)(lc[j] - chunkBase);
        }
    }
}

// ---------------- Phase 3: prefilter 256->32 + parallel exact fp32 re-rank ----------------
// 8 rows/block, 32 lanes/row. Extraction shuffles use width=32 (row = half-wave).
__global__ __launch_bounds__(256) void knn_refine(
    const float* __restrict__ test, const float* __restrict__ train,
    const float* __restrict__ bsq, const unsigned* __restrict__ cand,
    int* __restrict__ out)
{
    __shared__ __align__(16) float sArow[RPB * K_DIM];   // 8 KB
    __shared__ int sSel[RPB * 32];                       // 1 KB

    const int tid = threadIdx.x;
    const int rowBase = blockIdx.x * RPB;
    const int r = tid >> 5;          // row 0..7
    const int sub = tid & 31;        // lane within row

    // stage 8 test rows (coalesced: 512 float4, 2 per thread)
    {
        const float4* src = (const float4*)(test + (size_t)rowBase * K_DIM);
        float4* dst = (float4*)sArow;
        dst[tid] = src[tid];
        dst[256 + tid] = src[256 + tid];
    }

    // load this thread's 8 candidate keys -> u64 lex keys (val20 . gidx16)
    u64 ek[8];
    {
        const unsigned* cp = cand + (size_t)(rowBase + r) * 256 + sub * 8;
        #pragma unroll
        for (int j = 0; j < 8; ++j) {
            const unsigned k = cp[j];
            const int chunkId = (sub * 8 + j) >> 4;
            const unsigned gidx = (unsigned)(chunkId * CHUNK_N) + (k & 0xFFFu);
            ek[j] = ((u64)(k & 0xFFFFF000u) << 8) | gidx;
        }
    }
    __syncthreads();

    // approx-top-32 of 256 per row: 32 extraction rounds over 32 lanes
    for (int sel = 0; sel < 32; ++sel) {
        u64 bk = ek[0];
        #pragma unroll
        for (int j = 1; j < 8; ++j) bk = (ek[j] < bk) ? ek[j] : bk;
        #pragma unroll
        for (int off = 16; off > 0; off >>= 1) {
            const u64 ok = __shfl_xor(bk, off, 32);
            bk = (ok < bk) ? ok : bk;
        }
        if (sub == 0) sSel[r * 32 + sel] = (int)(bk & 0xFFFFULL);
        #pragma unroll
        for (int j = 0; j < 8; ++j)       // keys unique -> one lane clears one slot
            if (ek[j] == bk) ek[j] = ~0ULL;
    }
    __syncthreads();

    // exact reference-emulating chain: one candidate per thread
    const int gidx = sSel[r * 32 + sub];
    const float* arow = sArow + r * K_DIM;
    const float ta = np_pw_sq128(arow) + np_pw_sq128(arow + 128);
    const float tb = bsq[gidx];

    const float4* bp = (const float4*)(train + (size_t)gidx * K_DIM);
    const float4* ap = (const float4*)arow;
    float c = 0.0f;
    #pragma unroll 8
    for (int k = 0; k < K_DIM / 4; ++k) {
        const float4 a = ap[k];
        const float4 b = bp[k];
        c = fmaf(a.x, b.x, c); c = fmaf(a.y, b.y, c);
        c = fmaf(a.z, b.z, c); c = fmaf(a.w, b.w, c);
    }
    float d32;
    {
        #pragma clang fp contract(off)
        const float t = ta + tb;
        float s = t - 2.0f * c;
        s = fmaxf(s, 0.0f);
        d32 = sqrtf(s);
    }

    // final lex (d32, gidx) top-16 per row over 32 lanes
    u64 fk = ((u64)__float_as_uint(d32) << 32) | (unsigned)gidx;
    for (int sel = 0; sel < 16; ++sel) {
        u64 bk = fk;
        #pragma unroll
        for (int off = 16; off > 0; off >>= 1) {
            const u64 ok = __shfl_xor(bk, off, 32);
            bk = (ok < bk) ? ok : bk;
        }
        if (sub == 0) out[(size_t)(rowBase + r) * 16 + sel] = (int)(bk & 0xFFFFFFFFULL);
        if (fk == bk) fk = ~0ULL;
    }
}

// ---------------- launch ----------------
extern "C" void kernel_launch(void* const* d_in, const int* in_sizes, int n_in,
                              void* d_out, int out_size, void* d_ws, size_t ws_size,
                              hipStream_t stream)
{
    const float* Xtrain = (const float*)d_in[0];   // [65536, 256]
    const float* Xtest  = (const float*)d_in[1];   // [4096, 256]
    int* out = (int*)d_out;                        // [4096, 16] int32

    const size_t OFF_TRAINBF = 0;                              // 33,554,432 B
    const size_t OFF_TESTBF  = 33554432;                       //  2,097,152 B
    const size_t OFF_BSQ     = 35651584;                       //    262,144 B
    const size_t OFF_CAND    = 35913728;                       //  4,194,304 B
    const size_t NEED        = 40108032;
    if (ws_size < NEED) return;

    char* ws = (char*)d_ws;
    ushort_t* trainBf = (ushort_t*)(ws + OFF_TRAINBF);
    ushort_t* testBf  = (ushort_t*)(ws + OFF_TESTBF);
    float*    bsq     = (float*)(ws + OFF_BSQ);
    unsigned* cand    = (unsigned*)(ws + OFF_CAND);

    convert_bf16<<<dim3(N_TRAIN / 4), dim3(256), 0, stream>>>(Xtrain, trainBf, N_TRAIN);
    convert_bf16<<<dim3(N_TEST / 4), dim3(256), 0, stream>>>(Xtest, testBf, N_TEST);
    train_sq_np<<<dim3(N_TRAIN / 256), dim3(256), 0, stream>>>(Xtrain, bsq);
    knn_approx<<<dim3((N_TEST / TM) * NCHUNK), dim3(256), 0, stream>>>(testBf, trainBf, bsq, cand);
    knn_refine<<<dim3(N_TEST / RPB), dim3(256), 0, stream>>>(Xtest, Xtrain, bsq, cand, out);
}

// Round 9
// 629.886 us; speedup vs baseline: 1.5651x; 1.0960x over previous
//
#include <hip/hip_runtime.h>
#include <hip/hip_bf16.h>

// KNN top-16: X_test[4096,256] vs X_train[65536,256], fp32 in, int32 idx out.
// Phase 1: fp32->bf16 convert; fp32 train row sq-norms (numpy-pairwise emulation).
// Phase 2: bf16 MFMA approx score GEMM (v = ||b||^2 - 2 a.b), restructured K-loop:
//          A-frags loaded per-panel straight from global into REGISTERS (no LDS
//          round trip, no A barriers), B staged via global_load_lds(16B) with the
//          XOR swizzle applied on addresses, BK=128 (2 panels/iter, 5 barriers/iter
//          vs r8's 9). Push-based per-row top-16 on PACKED u32 keys
//          (bits(v+1024)&0xFFFFF000 | colInChunk — monotone, == final cand format).
// Phase 3: 8 rows/block: approx-top-32 prefilter of 256 candidates (width-32
//          shuffles), then 256 parallel exact fp32-reference-emulating chains,
//          lex (d32, gidx) top-16 (fp32 snap-ties resolve by index like top_k).

typedef short bf16x8 __attribute__((ext_vector_type(8)));
typedef float f32x4 __attribute__((ext_vector_type(4)));
typedef unsigned short ushort_t;
typedef unsigned long long u64;

#define K_DIM     256
#define N_TRAIN   65536
#define N_TEST    4096
#define TM        64
#define TN        128
#define NCHUNK    16
#define CHUNK_N   (N_TRAIN / NCHUNK)      // 4096
#define ITERS     (CHUNK_N / TN)          // 32
#define LISTN     16
#define QCAP      8
#define RPB       8                        // refine rows per block

// ---------------- numpy pairwise sum emulation (fp32, contract OFF) ----------------
static __device__ __forceinline__ float np_pw_sq128(const float* __restrict__ x) {
    #pragma clang fp contract(off)
    float r0, r1, r2, r3, r4, r5, r6, r7;
    {
        const float4 a = *(const float4*)(x + 0);
        const float4 b = *(const float4*)(x + 4);
        r0 = a.x * a.x; r1 = a.y * a.y; r2 = a.z * a.z; r3 = a.w * a.w;
        r4 = b.x * b.x; r5 = b.y * b.y; r6 = b.z * b.z; r7 = b.w * b.w;
    }
    for (int i = 8; i < 128; i += 8) {
        const float4 a = *(const float4*)(x + i);
        const float4 b = *(const float4*)(x + i + 4);
        r0 = r0 + a.x * a.x; r1 = r1 + a.y * a.y;
        r2 = r2 + a.z * a.z; r3 = r3 + a.w * a.w;
        r4 = r4 + b.x * b.x; r5 = r5 + b.y * b.y;
        r6 = r6 + b.z * b.z; r7 = r7 + b.w * b.w;
    }
    return ((r0 + r1) + (r2 + r3)) + ((r4 + r5) + (r6 + r7));
}

// ---------------- async global->LDS, 16B per lane ----------------
static __device__ __forceinline__ void gld_lds16(const ushort_t* g, ushort_t* l) {
    __builtin_amdgcn_global_load_lds(
        (const __attribute__((address_space(1))) unsigned int*)g,
        (__attribute__((address_space(3))) unsigned int*)l,
        16, 0, 0);
}

// ---------------- Phase 1a: convert ----------------
static __device__ __forceinline__ ushort_t f2bf(float x) {
    unsigned u = __float_as_uint(x);
    return (ushort_t)((u + 0x7FFFu + ((u >> 16) & 1u)) >> 16);  // RNE
}

__global__ __launch_bounds__(256) void convert_bf16(
    const float* __restrict__ src, ushort_t* __restrict__ dst, int nrows)
{
    const int wid = threadIdx.x >> 6, lane = threadIdx.x & 63;
    const int row = blockIdx.x * 4 + wid;
    if (row >= nrows) return;
    const float4 f = *(const float4*)(src + (size_t)row * K_DIM + lane * 4);
    ushort4 h;
    h.x = f2bf(f.x); h.y = f2bf(f.y); h.z = f2bf(f.z); h.w = f2bf(f.w);
    *(ushort4*)(dst + (size_t)row * K_DIM + lane * 4) = h;
}

// ---------------- Phase 1b: train row norms, numpy-pairwise fp32 ----------------
__global__ __launch_bounds__(256) void train_sq_np(
    const float* __restrict__ train, float* __restrict__ bsq)
{
    const int r = blockIdx.x * 256 + threadIdx.x;
    const float* x = train + (size_t)r * K_DIM;
    bsq[r] = np_pw_sq128(x) + np_pw_sq128(x + 128);
}

// ---------------- Phase 2: approx GEMM + push-based per-row top-16 ----------------
// 256 thr, 2x2 wave grid, wave-tile 32x64. A in registers, B in 32 KB LDS panel.
__global__ __launch_bounds__(256, 4) void knn_approx(
    const ushort_t* __restrict__ testBf, const ushort_t* __restrict__ trainBf,
    const float* __restrict__ bsq, unsigned* __restrict__ cand)
{
    __shared__ __align__(16) ushort_t sB[TN * 128];    // 32 KB: 128 cols x 128 k
    __shared__ unsigned sQ  [TM * QCAP];               // 2 KB packed keys
    __shared__ int      sQn [TM];
    __shared__ unsigned sCutP[TM];
    __shared__ float    sBsq[TN];

    const int tid = threadIdx.x;
    const int bx = blockIdx.x;
    const int chunk = bx & (NCHUNK - 1);
    const int rowTile = bx >> 4;                       // 0..63
    const int rowBase = rowTile * TM;
    const int chunkBase = chunk * CHUNK_N;
    const int lane = tid & 63;
    const int wid = tid >> 6;
    const int quad = lane >> 4;
    const int l15 = lane & 15;
    const int wm = wid >> 1;           // 0..1 (row 32-half)
    const int wn = wid & 1;            // 0..1 (col 64-half)

    if (tid < TM) { sQn[tid] = 0; sCutP[tid] = 0xFFFFFFFFu; }

    // owner (tid<64) register-resident sorted-ascending packed top-16
    unsigned lk[LISTN];
    #pragma unroll
    for (int j = 0; j < LISTN; ++j) lk[j] = 0xFFFFF000u | (unsigned)j;

    // A frag base pointers (immediate offsets cover p*256B + s2*64B)
    const ushort_t* aB0 = testBf + (size_t)(rowBase + wm * 32 + 0  + l15) * K_DIM + quad * 8;
    const ushort_t* aB1 = testBf + (size_t)(rowBase + wm * 32 + 16 + l15) * K_DIM + quad * 8;

    // B staging constants: slot s=c*256+tid -> r=c*16+(tid>>4), u=tid&15
    const int rt = tid >> 4;
    const int ub = tid & 15;
    const int kg = ((ub & 7) ^ (rt & 7)) | (ub & 8);   // c-independent

    for (int it = 0; it < ITERS; ++it) {
        const int colBase = chunkBase + it * TN;
        f32x4 acc[2][4] = {};

        #pragma unroll
        for (int p = 0; p < 2; ++p) {
            if (p) __syncthreads();    // p0 covered by prior selection barrier
            {
                const ushort_t* gb = trainBf + (size_t)(colBase + rt) * K_DIM + p * 128 + kg * 8;
                ushort_t* lb = sB + (size_t)tid * 8;
                #pragma unroll
                for (int c = 0; c < 8; ++c)
                    gld_lds16(gb + (size_t)c * 16 * K_DIM, lb + (size_t)c * 2048);
            }
            if (p == 0 && tid < TN) sBsq[tid] = bsq[colBase + tid];
            __syncthreads();           // drains vmcnt -> LDS valid

            // A frags for this panel: registers, straight from global (L2-hot)
            bf16x8 af0[4], af1[4];
            #pragma unroll
            for (int s2 = 0; s2 < 4; ++s2) {
                af0[s2] = *(const bf16x8*)(aB0 + p * 128 + s2 * 32);
                af1[s2] = *(const bf16x8*)(aB1 + p * 128 + s2 * 32);
            }
            #pragma unroll
            for (int s2 = 0; s2 < 4; ++s2) {
                #pragma unroll
                for (int in = 0; in < 4; ++in) {
                    const int col = wn * 64 + in * 16 + l15;
                    const int g = s2 * 4 + quad;
                    const int pg = ((g & 7) ^ (col & 7)) | (g & 8);
                    const bf16x8 bfr = *(const bf16x8*)(sB + (size_t)col * 128 + pg * 8);
                    acc[0][in] = __builtin_amdgcn_mfma_f32_16x16x32_bf16(af0[s2], bfr, acc[0][in], 0, 0, 0);
                    acc[1][in] = __builtin_amdgcn_mfma_f32_16x16x32_bf16(af1[s2], bfr, acc[1][in], 0, 0, 0);
                }
            }
        }

        // v = bsq[col] - 2*dot; C layout: row=quad*4+r, col=l15
        float bq[4];
        unsigned cpk[4];
        #pragma unroll
        for (int in = 0; in < 4; ++in) {
            bq[in] = sBsq[wn * 64 + in * 16 + l15];
            cpk[in] = (unsigned)(it * TN + wn * 64 + in * 16 + l15);   // 12-bit col-in-chunk
        }
        #pragma unroll
        for (int im = 0; im < 2; ++im)
            #pragma unroll
            for (int in = 0; in < 4; ++in)
                #pragma unroll
                for (int r = 0; r < 4; ++r)
                    acc[im][in][r] = fmaf(-2.0f, acc[im][in][r], bq[in]);

        // ---- push-based selection on packed keys; bounded retry rounds ----
        unsigned pend = 0xFFFFFFFFu;               // 32 values/thread, bits 0..31
        while (true) {
            unsigned cutr[2][4];
            #pragma unroll
            for (int im = 0; im < 2; ++im)
                #pragma unroll
                for (int r = 0; r < 4; ++r)
                    cutr[im][r] = sCutP[wm * 32 + im * 16 + quad * 4 + r];

            unsigned np = 0u;
            #pragma unroll
            for (int im = 0; im < 2; ++im)
                #pragma unroll
                for (int in = 0; in < 4; ++in)
                    #pragma unroll
                    for (int r = 0; r < 4; ++r) {
                        const int bit = (im * 4 + in) * 4 + r;
                        if ((pend >> bit) & 1u) {
                            const unsigned key =
                                (__float_as_uint(acc[im][in][r] + 1024.0f) & 0xFFFFF000u) | cpk[in];
                            if (key < cutr[im][r]) {
                                const int row = wm * 32 + im * 16 + quad * 4 + r;
                                const int pos = atomicAdd(&sQn[row], 1);
                                if (pos < QCAP) sQ[row * QCAP + pos] = key;
                                else            np |= (1u << bit);
                            }
                        }
                    }
            __syncthreads();                       // pushes done before drain
            if (tid < TM) {
                const int n = min(sQn[tid], QCAP);
                for (int e = 0; e < n; ++e) {
                    const unsigned k = sQ[tid * QCAP + e];
                    if (k < lk[LISTN - 1]) {
                        lk[LISTN - 1] = k;
                        #pragma unroll
                        for (int j = LISTN - 1; j > 0; --j)
                            if (lk[j] < lk[j - 1]) {
                                const unsigned t = lk[j]; lk[j] = lk[j - 1]; lk[j - 1] = t;
                            }
                    }
                }
                sQn[tid] = 0;
                sCutP[tid] = lk[LISTN - 1];
            }
            if (!__syncthreads_or(np != 0u)) break;   // also publishes sCutP/sQn
            pend = np;
        }
    }

    if (tid < TM) {
        #pragma unroll
        for (int j = 0; j < LISTN; ++j)
            cand[(size_t)(rowBase + tid) * (NCHUNK * LISTN) + chunk * LISTN + j] = lk[j];
    }
}

// ---------------- Phase 3: prefilter 256->32 + parallel exact fp32 re-rank ----------------
// 8 rows/block, 32 lanes/row; width-32 shuffles.
__global__ __launch_bounds__(256) void knn_refine(
    const float* __restrict__ test, const float* __restrict__ train,
    const float* __restrict__ bsq, const unsigned* __restrict__ cand,
    int* __restrict__ out)
{
    __shared__ __align__(16) float sArow[RPB * K_DIM];   // 8 KB
    __shared__ int sSel[RPB * 32];                       // 1 KB

    const int tid = threadIdx.x;
    const int rowBase = blockIdx.x * RPB;
    const int r = tid >> 5;          // row 0..7
    const int sub = tid & 31;        // lane within row

    {
        const float4* src = (const float4*)(test + (size_t)rowBase * K_DIM);
        float4* dst = (float4*)sArow;
        dst[tid] = src[tid];
        dst[256 + tid] = src[256 + tid];
    }

    u64 ek[8];
    {
        const unsigned* cp = cand + (size_t)(rowBase + r) * 256 + sub * 8;
        #pragma unroll
        for (int j = 0; j < 8; ++j) {
            const unsigned k = cp[j];
            const int chunkId = (sub * 8 + j) >> 4;
            const unsigned gidx = (unsigned)(chunkId * CHUNK_N) + (k & 0xFFFu);
            ek[j] = ((u64)(k & 0xFFFFF000u) << 8) | gidx;
        }
    }
    __syncthreads();

    for (int sel = 0; sel < 32; ++sel) {
        u64 bk = ek[0];
        #pragma unroll
        for (int j = 1; j < 8; ++j) bk = (ek[j] < bk) ? ek[j] : bk;
        #pragma unroll
        for (int off = 16; off > 0; off >>= 1) {
            const u64 ok = __shfl_xor(bk, off, 32);
            bk = (ok < bk) ? ok : bk;
        }
        if (sub == 0) sSel[r * 32 + sel] = (int)(bk & 0xFFFFULL);
        #pragma unroll
        for (int j = 0; j < 8; ++j)
            if (ek[j] == bk) ek[j] = ~0ULL;
    }
    __syncthreads();

    const int gidx = sSel[r * 32 + sub];
    const float* arow = sArow + r * K_DIM;
    const float ta = np_pw_sq128(arow) + np_pw_sq128(arow + 128);
    const float tb = bsq[gidx];

    const float4* bp = (const float4*)(train + (size_t)gidx * K_DIM);
    const float4* ap = (const float4*)arow;
    float c = 0.0f;
    #pragma unroll 8
    for (int k = 0; k < K_DIM / 4; ++k) {
        const float4 a = ap[k];
        const float4 b = bp[k];
        c = fmaf(a.x, b.x, c); c = fmaf(a.y, b.y, c);
        c = fmaf(a.z, b.z, c); c = fmaf(a.w, b.w, c);
    }
    float d32;
    {
        #pragma clang fp contract(off)
        const float t = ta + tb;
        float s = t - 2.0f * c;
        s = fmaxf(s, 0.0f);
        d32 = sqrtf(s);
    }

    u64 fk = ((u64)__float_as_uint(d32) << 32) | (unsigned)gidx;
    for (int sel = 0; sel < 16; ++sel) {
        u64 bk = fk;
        #pragma unroll
        for (int off = 16; off > 0; off >>= 1) {
            const u64 ok = __shfl_xor(bk, off, 32);
            bk = (ok < bk) ? ok : bk;
        }
        if (sub == 0) out[(size_t)(rowBase + r) * 16 + sel] = (int)(bk & 0xFFFFFFFFULL);
        if (fk == bk) fk = ~0ULL;
    }
}

// ---------------- launch ----------------
extern "C" void kernel_launch(void* const* d_in, const int* in_sizes, int n_in,
                              void* d_out, int out_size, void* d_ws, size_t ws_size,
                              hipStream_t stream)
{
    const float* Xtrain = (const float*)d_in[0];   // [65536, 256]
    const float* Xtest  = (const float*)d_in[1];   // [4096, 256]
    int* out = (int*)d_out;                        // [4096, 16] int32

    const size_t OFF_TRAINBF = 0;                              // 33,554,432 B
    const size_t OFF_TESTBF  = 33554432;                       //  2,097,152 B
    const size_t OFF_BSQ     = 35651584;                       //    262,144 B
    const size_t OFF_CAND    = 35913728;                       //  4,194,304 B
    const size_t NEED        = 40108032;
    if (ws_size < NEED) return;

    char* ws = (char*)d_ws;
    ushort_t* trainBf = (ushort_t*)(ws + OFF_TRAINBF);
    ushort_t* testBf  = (ushort_t*)(ws + OFF_TESTBF);
    float*    bsq     = (float*)(ws + OFF_BSQ);
    unsigned* cand    = (unsigned*)(ws + OFF_CAND);

    convert_bf16<<<dim3(N_TRAIN / 4), dim3(256), 0, stream>>>(Xtrain, trainBf, N_TRAIN);
    convert_bf16<<<dim3(N_TEST / 4), dim3(256), 0, stream>>>(Xtest, testBf, N_TEST);
    train_sq_np<<<dim3(N_TRAIN / 256), dim3(256), 0, stream>>>(Xtrain, bsq);
    knn_approx<<<dim3((N_TEST / TM) * NCHUNK), dim3(256), 0, stream>>>(testBf, trainBf, bsq, cand);
    knn_refine<<<dim3(N_TEST / RPB), dim3(256), 0, stream>>>(Xtest, Xtrain, bsq, cand, out);
}

// Round 10
// 563.590 us; speedup vs baseline: 1.7492x; 1.1176x over previous
//
#include <hip/hip_runtime.h>
#include <hip/hip_bf16.h>

// KNN top-16: X_test[4096,256] vs X_train[65536,256], fp32 in, int32 idx out.
// Phase 1: fp32->bf16 convert; fp32 train row sq-norms (numpy-pairwise emulation).
// Phase 2: bf16 MFMA approx score GEMM (v = ||b||^2 - 2 a.b). K-loop structure:
//          A-fragments PRELOADED INTO REGISTERS once per block (64 VGPR; r9's
//          in-loop A-from-global refetch thrashed L2: FETCH 830 MB). B staged
//          per 128-k panel via global_load_lds(16B), XOR swizzle on addresses.
//          Push-based per-row top-16 on packed u32 keys; owner lists in LDS
//          (loaded to regs only on non-empty queue) to keep VGPR <= 128.
// Phase 3: 8 rows/block: approx-top-32 prefilter of 256 candidates (width-32
//          shuffles), then 256 parallel exact fp32-reference-emulating chains,
//          lex (d32, gidx) top-16 (fp32 snap-ties resolve by index like top_k).

typedef short bf16x8 __attribute__((ext_vector_type(8)));
typedef float f32x4 __attribute__((ext_vector_type(4)));
typedef unsigned short ushort_t;
typedef unsigned long long u64;

#define K_DIM     256
#define N_TRAIN   65536
#define N_TEST    4096
#define TM        64
#define TN        128
#define NCHUNK    16
#define CHUNK_N   (N_TRAIN / NCHUNK)      // 4096
#define ITERS     (CHUNK_N / TN)          // 32
#define LISTN     16
#define QCAP      8
#define RPB       8                        // refine rows per block

// ---------------- numpy pairwise sum emulation (fp32, contract OFF) ----------------
static __device__ __forceinline__ float np_pw_sq128(const float* __restrict__ x) {
    #pragma clang fp contract(off)
    float r0, r1, r2, r3, r4, r5, r6, r7;
    {
        const float4 a = *(const float4*)(x + 0);
        const float4 b = *(const float4*)(x + 4);
        r0 = a.x * a.x; r1 = a.y * a.y; r2 = a.z * a.z; r3 = a.w * a.w;
        r4 = b.x * b.x; r5 = b.y * b.y; r6 = b.z * b.z; r7 = b.w * b.w;
    }
    for (int i = 8; i < 128; i += 8) {
        const float4 a = *(const float4*)(x + i);
        const float4 b = *(const float4*)(x + i + 4);
        r0 = r0 + a.x * a.x; r1 = r1 + a.y * a.y;
        r2 = r2 + a.z * a.z; r3 = r3 + a.w * a.w;
        r4 = r4 + b.x * b.x; r5 = r5 + b.y * b.y;
        r6 = r6 + b.z * b.z; r7 = r7 + b.w * b.w;
    }
    return ((r0 + r1) + (r2 + r3)) + ((r4 + r5) + (r6 + r7));
}

// ---------------- async global->LDS, 16B per lane ----------------
static __device__ __forceinline__ void gld_lds16(const ushort_t* g, ushort_t* l) {
    __builtin_amdgcn_global_load_lds(
        (const __attribute__((address_space(1))) unsigned int*)g,
        (__attribute__((address_space(3))) unsigned int*)l,
        16, 0, 0);
}

// ---------------- Phase 1a: convert ----------------
static __device__ __forceinline__ ushort_t f2bf(float x) {
    unsigned u = __float_as_uint(x);
    return (ushort_t)((u + 0x7FFFu + ((u >> 16) & 1u)) >> 16);  // RNE
}

__global__ __launch_bounds__(256) void convert_bf16(
    const float* __restrict__ src, ushort_t* __restrict__ dst, int nrows)
{
    const int wid = threadIdx.x >> 6, lane = threadIdx.x & 63;
    const int row = blockIdx.x * 4 + wid;
    if (row >= nrows) return;
    const float4 f = *(const float4*)(src + (size_t)row * K_DIM + lane * 4);
    ushort4 h;
    h.x = f2bf(f.x); h.y = f2bf(f.y); h.z = f2bf(f.z); h.w = f2bf(f.w);
    *(ushort4*)(dst + (size_t)row * K_DIM + lane * 4) = h;
}

// ---------------- Phase 1b: train row norms, numpy-pairwise fp32 ----------------
__global__ __launch_bounds__(256) void train_sq_np(
    const float* __restrict__ train, float* __restrict__ bsq)
{
    const int r = blockIdx.x * 256 + threadIdx.x;
    const float* x = train + (size_t)r * K_DIM;
    bsq[r] = np_pw_sq128(x) + np_pw_sq128(x + 128);
}

// ---------------- Phase 2: approx GEMM + push-based per-row top-16 ----------------
// 256 thr, 2x2 wave grid, wave-tile 32x64. A in registers (preloaded), B in 32 KB LDS.
__global__ __launch_bounds__(256, 4) void knn_approx(
    const ushort_t* __restrict__ testBf, const ushort_t* __restrict__ trainBf,
    const float* __restrict__ bsq, unsigned* __restrict__ cand)
{
    __shared__ __align__(16) ushort_t sB[TN * 128];    // 32 KB: 128 cols x 128 k
    __shared__ __align__(16) unsigned sLv[TM * LISTN]; // 4 KB owner top-16 lists
    __shared__ unsigned sQ  [TM * QCAP];               // 2 KB packed-key queues
    __shared__ int      sQn [TM];
    __shared__ unsigned sCutP[TM];
    __shared__ float    sBsq[TN];

    const int tid = threadIdx.x;
    const int bx = blockIdx.x;
    const int chunk = bx & (NCHUNK - 1);
    const int rowTile = bx >> 4;                       // 0..63
    const int rowBase = rowTile * TM;
    const int chunkBase = chunk * CHUNK_N;
    const int lane = tid & 63;
    const int wid = tid >> 6;
    const int quad = lane >> 4;
    const int l15 = lane & 15;
    const int wm = wid >> 1;           // 0..1 (row 32-half)
    const int wn = wid & 1;            // 0..1 (col 64-half)

    if (tid < TM) {
        sQn[tid] = 0;
        sCutP[tid] = 0xFFFFFFFFu;
        #pragma unroll
        for (int j = 0; j < LISTN; ++j)
            sLv[tid * LISTN + j] = 0xFFFFF000u | (unsigned)j;   // sentinel keys
    }

    // ---- preload ALL A-fragments into registers (once; 64 VGPR) ----
    bf16x8 af[2][2][4];   // [im][panel][s2]
    {
        const ushort_t* a0 = testBf + (size_t)(rowBase + wm * 32 + l15) * K_DIM + quad * 8;
        const ushort_t* a1 = a0 + (size_t)16 * K_DIM;
        #pragma unroll
        for (int p = 0; p < 2; ++p)
            #pragma unroll
            for (int s2 = 0; s2 < 4; ++s2) {
                af[0][p][s2] = *(const bf16x8*)(a0 + p * 128 + s2 * 32);
                af[1][p][s2] = *(const bf16x8*)(a1 + p * 128 + s2 * 32);
            }
    }

    // B staging constants: slot s = c*256+tid -> col = c*16 + (tid>>4), group u = tid&15
    const int rt = tid >> 4;
    const int ub = tid & 15;
    const int kg = ((ub & 7) ^ (rt & 7)) | (ub & 8);   // c-independent

    for (int it = 0; it < ITERS; ++it) {
        const int colBase = chunkBase + it * TN;
        f32x4 acc[2][4] = {};

        #pragma unroll
        for (int p = 0; p < 2; ++p) {
            if (p) __syncthreads();    // protect sB against prior panel's reads
            {
                const ushort_t* gb = trainBf + (size_t)(colBase + rt) * K_DIM + p * 128 + kg * 8;
                ushort_t* lb = sB + (size_t)tid * 8;
                #pragma unroll
                for (int c = 0; c < 8; ++c)
                    gld_lds16(gb + (size_t)c * 16 * K_DIM, lb + (size_t)c * 2048);
            }
            if (p == 0 && tid < TN) sBsq[tid] = bsq[colBase + tid];
            __syncthreads();           // drains vmcnt -> LDS valid

            #pragma unroll
            for (int s2 = 0; s2 < 4; ++s2) {
                #pragma unroll
                for (int in = 0; in < 4; ++in) {
                    const int col = wn * 64 + in * 16 + l15;
                    const int g = s2 * 4 + quad;
                    const int pg = ((g & 7) ^ (col & 7)) | (g & 8);
                    const bf16x8 bfr = *(const bf16x8*)(sB + (size_t)col * 128 + pg * 8);
                    acc[0][in] = __builtin_amdgcn_mfma_f32_16x16x32_bf16(af[0][p][s2], bfr, acc[0][in], 0, 0, 0);
                    acc[1][in] = __builtin_amdgcn_mfma_f32_16x16x32_bf16(af[1][p][s2], bfr, acc[1][in], 0, 0, 0);
                }
            }
        }

        // v = bsq[col] - 2*dot; C layout: row=quad*4+r, col=l15
        float bq[4];
        unsigned cpk[4];
        #pragma unroll
        for (int in = 0; in < 4; ++in) {
            bq[in] = sBsq[wn * 64 + in * 16 + l15];
            cpk[in] = (unsigned)(it * TN + wn * 64 + in * 16 + l15);   // 12-bit col-in-chunk
        }
        #pragma unroll
        for (int im = 0; im < 2; ++im)
            #pragma unroll
            for (int in = 0; in < 4; ++in)
                #pragma unroll
                for (int r = 0; r < 4; ++r)
                    acc[im][in][r] = fmaf(-2.0f, acc[im][in][r], bq[in]);

        // ---- push-based selection on packed keys; bounded retry rounds ----
        unsigned pend = 0xFFFFFFFFu;               // 32 values/thread
        while (true) {
            unsigned cutr[2][4];
            #pragma unroll
            for (int im = 0; im < 2; ++im)
                #pragma unroll
                for (int r = 0; r < 4; ++r)
                    cutr[im][r] = sCutP[wm * 32 + im * 16 + quad * 4 + r];

            unsigned np = 0u;
            #pragma unroll
            for (int im = 0; im < 2; ++im)
                #pragma unroll
                for (int in = 0; in < 4; ++in)
                    #pragma unroll
                    for (int r = 0; r < 4; ++r) {
                        const int bit = (im * 4 + in) * 4 + r;
                        if ((pend >> bit) & 1u) {
                            const unsigned key =
                                (__float_as_uint(acc[im][in][r] + 1024.0f) & 0xFFFFF000u) | cpk[in];
                            if (key < cutr[im][r]) {
                                const int row = wm * 32 + im * 16 + quad * 4 + r;
                                const int pos = atomicAdd(&sQn[row], 1);
                                if (pos < QCAP) sQ[row * QCAP + pos] = key;
                                else            np |= (1u << bit);
                            }
                        }
                    }
            __syncthreads();                       // pushes done before drain
            if (tid < TM) {
                const int n = min(sQn[tid], QCAP);
                if (n > 0) {                       // empty queue (steady state) -> skip
                    unsigned lk[LISTN];            // transient regs: 4x ds_read_b128
                    #pragma unroll
                    for (int j = 0; j < LISTN; ++j) lk[j] = sLv[tid * LISTN + j];
                    for (int e = 0; e < n; ++e) {
                        const unsigned k = sQ[tid * QCAP + e];
                        if (k < lk[LISTN - 1]) {
                            lk[LISTN - 1] = k;
                            #pragma unroll
                            for (int j = LISTN - 1; j > 0; --j)
                                if (lk[j] < lk[j - 1]) {
                                    const unsigned t = lk[j]; lk[j] = lk[j - 1]; lk[j - 1] = t;
                                }
                        }
                    }
                    #pragma unroll
                    for (int j = 0; j < LISTN; ++j) sLv[tid * LISTN + j] = lk[j];
                    sQn[tid] = 0;
                    sCutP[tid] = lk[LISTN - 1];
                }
            }
            if (!__syncthreads_or(np != 0u)) break;   // also publishes sCutP/sQn
            pend = np;
        }
    }

    if (tid < TM) {
        #pragma unroll
        for (int j = 0; j < LISTN; ++j)
            cand[(size_t)(rowBase + tid) * (NCHUNK * LISTN) + chunk * LISTN + j] =
                sLv[tid * LISTN + j];
    }
}

// ---------------- Phase 3: prefilter 256->32 + parallel exact fp32 re-rank ----------------
// 8 rows/block, 32 lanes/row; width-32 shuffles.
__global__ __launch_bounds__(256) void knn_refine(
    const float* __restrict__ test, const float* __restrict__ train,
    const float* __restrict__ bsq, const unsigned* __restrict__ cand,
    int* __restrict__ out)
{
    __shared__ __align__(16) float sArow[RPB * K_DIM];   // 8 KB
    __shared__ int sSel[RPB * 32];                       // 1 KB

    const int tid = threadIdx.x;
    const int rowBase = blockIdx.x * RPB;
    const int r = tid >> 5;          // row 0..7
    const int sub = tid & 31;        // lane within row

    {
        const float4* src = (const float4*)(test + (size_t)rowBase * K_DIM);
        float4* dst = (float4*)sArow;
        dst[tid] = src[tid];
        dst[256 + tid] = src[256 + tid];
    }

    u64 ek[8];
    {
        const unsigned* cp = cand + (size_t)(rowBase + r) * 256 + sub * 8;
        #pragma unroll
        for (int j = 0; j < 8; ++j) {
            const unsigned k = cp[j];
            const int chunkId = (sub * 8 + j) >> 4;
            const unsigned gidx = (unsigned)(chunkId * CHUNK_N) + (k & 0xFFFu);
            ek[j] = ((u64)(k & 0xFFFFF000u) << 8) | gidx;
        }
    }
    __syncthreads();

    for (int sel = 0; sel < 32; ++sel) {
        u64 bk = ek[0];
        #pragma unroll
        for (int j = 1; j < 8; ++j) bk = (ek[j] < bk) ? ek[j] : bk;
        #pragma unroll
        for (int off = 16; off > 0; off >>= 1) {
            const u64 ok = __shfl_xor(bk, off, 32);
            bk = (ok < bk) ? ok : bk;
        }
        if (sub == 0) sSel[r * 32 + sel] = (int)(bk & 0xFFFFULL);
        #pragma unroll
        for (int j = 0; j < 8; ++j)
            if (ek[j] == bk) ek[j] = ~0ULL;
    }
    __syncthreads();

    const int gidx = sSel[r * 32 + sub];
    const float* arow = sArow + r * K_DIM;
    const float ta = np_pw_sq128(arow) + np_pw_sq128(arow + 128);
    const float tb = bsq[gidx];

    const float4* bp = (const float4*)(train + (size_t)gidx * K_DIM);
    const float4* ap = (const float4*)arow;
    float c = 0.0f;
    #pragma unroll 8
    for (int k = 0; k < K_DIM / 4; ++k) {
        const float4 a = ap[k];
        const float4 b = bp[k];
        c = fmaf(a.x, b.x, c); c = fmaf(a.y, b.y, c);
        c = fmaf(a.z, b.z, c); c = fmaf(a.w, b.w, c);
    }
    float d32;
    {
        #pragma clang fp contract(off)
        const float t = ta + tb;
        float s = t - 2.0f * c;
        s = fmaxf(s, 0.0f);
        d32 = sqrtf(s);
    }

    u64 fk = ((u64)__float_as_uint(d32) << 32) | (unsigned)gidx;
    for (int sel = 0; sel < 16; ++sel) {
        u64 bk = fk;
        #pragma unroll
        for (int off = 16; off > 0; off >>= 1) {
            const u64 ok = __shfl_xor(bk, off, 32);
            bk = (ok < bk) ? ok : bk;
        }
        if (sub == 0) out[(size_t)(rowBase + r) * 16 + sel] = (int)(bk & 0xFFFFFFFFULL);
        if (fk == bk) fk = ~0ULL;
    }
}

// ---------------- launch ----------------
extern "C" void kernel_launch(void* const* d_in, const int* in_sizes, int n_in,
                              void* d_out, int out_size, void* d_ws, size_t ws_size,
                              hipStream_t stream)
{
    const float* Xtrain = (const float*)d_in[0];   // [65536, 256]
    const float* Xtest  = (const float*)d_in[1];   // [4096, 256]
    int* out = (int*)d_out;                        // [4096, 16] int32

    const size_t OFF_TRAINBF = 0;                              // 33,554,432 B
    const size_t OFF_TESTBF  = 33554432;                       //  2,097,152 B
    const size_t OFF_BSQ     = 35651584;                       //    262,144 B
    const size_t OFF_CAND    = 35913728;                       //  4,194,304 B
    const size_t NEED        = 40108032;
    if (ws_size < NEED) return;

    char* ws = (char*)d_ws;
    ushort_t* trainBf = (ushort_t*)(ws + OFF_TRAINBF);
    ushort_t* testBf  = (ushort_t*)(ws + OFF_TESTBF);
    float*    bsq     = (float*)(ws + OFF_BSQ);
    unsigned* cand    = (unsigned*)(ws + OFF_CAND);

    convert_bf16<<<dim3(N_TRAIN / 4), dim3(256), 0, stream>>>(Xtrain, trainBf, N_TRAIN);
    convert_bf16<<<dim3(N_TEST / 4), dim3(256), 0, stream>>>(Xtest, testBf, N_TEST);
    train_sq_np<<<dim3(N_TRAIN / 256), dim3(256), 0, stream>>>(Xtrain, bsq);
    knn_approx<<<dim3((N_TEST / TM) * NCHUNK), dim3(256), 0, stream>>>(testBf, trainBf, bsq, cand);
    knn_refine<<<dim3(N_TEST / RPB), dim3(256), 0, stream>>>(Xtest, Xtrain, bsq, cand, out);
}